// Round 8
// baseline (62.375 us; speedup 1.0000x reference)
//
#include <hip/hip_runtime.h>
#include <math.h>

#define TABN 512
#define LE 4             // LUT entries per block
#define RPW 16           // rows per wave -> 4096 waves = 1024 blocks = 4 blocks/CU, fully resident
#define D 1000
#define DV4 250          // 1000 floats = 250 float4; row stride 4000B is 16B-aligned

// ---------------- LUT kernel: wide layout, 128 blocks x 256 threads (R6, proven) -------
__global__ __launch_bounds__(256) void lut_kernel(
    const float* __restrict__ w1, const float* __restrict__ b1,
    const float* __restrict__ w2, const float* __restrict__ b2,
    const float* __restrict__ w3, const float* __restrict__ b3,
    const float* __restrict__ w4, const float* __restrict__ b4,
    float* __restrict__ lut)
{
    __shared__ float h1s[LE][512];      // 8 KB
    __shared__ float pl2[LE][4][64];    // 4 KB
    __shared__ float h2s[LE][64];       // 1 KB
    const int t  = threadIdx.x;
    const int k  = t & 63;              // layer-2 output unit
    const int jc = t >> 6;              // j-chunk 0..3 (one per wave)
    const int e0 = blockIdx.x * LE;

    float s[LE];
#pragma unroll
    for (int e = 0; e < LE; ++e)
        s[e] = -1.0f + 2.0f * (float)(e0 + e) / (float)(TABN - 1);

    // layer 1: 1 -> 512
#pragma unroll
    for (int j = t; j < 512; j += 256) {
        float wj = w1[j], bj = b1[j];
#pragma unroll
        for (int e = 0; e < LE; ++e) {
            float v = fmaf(wj, s[e], bj);
            h1s[e][j] = v > 0.0f ? v : 0.0f;
        }
    }
    __syncthreads();

    // layer 2: 512 -> 64, j split 4 ways across waves
    float pacc[LE] = {0.f, 0.f, 0.f, 0.f};
    const int jbase = jc * 128;
#pragma unroll 4
    for (int jj = 0; jj < 128; ++jj) {
        int j = jbase + jj;
        float w = w2[j * 64 + k];
#pragma unroll
        for (int e = 0; e < LE; ++e)
            pacc[e] = fmaf(w, h1s[e][j], pacc[e]);
    }
#pragma unroll
    for (int e = 0; e < LE; ++e) pl2[e][jc][k] = pacc[e];
    __syncthreads();

    if (t < 64) {
#pragma unroll
        for (int e = 0; e < LE; ++e) {
            float a = b2[k] + ((pl2[e][0][k] + pl2[e][1][k]) +
                               (pl2[e][2][k] + pl2[e][3][k]));
            h2s[e][k] = a > 0.0f ? a : 0.0f;
        }
    }
    __syncthreads();

    // layer 3 (64->32) + layer 4 (32->1): threads 0..127, e = t>>5, m = t&31
    if (t < 32 * LE) {
        const int e = t >> 5, m = t & 31;
        float a = b3[m];
#pragma unroll 4
        for (int kk = 0; kk < 64; ++kk)
            a = fmaf(w3[kk * 32 + m], h2s[e][kk], a);
        float h3 = a > 0.0f ? a : 0.0f;
        float part = h3 * w4[m];
#pragma unroll
        for (int off = 16; off >= 1; off >>= 1)
            part += __shfl_xor(part, off, 32);
        if (m == 0)
            lut[e0 + e] = 1.0f / (1.0f + expf(-(part + b4[0])));
    }
}

// ---------------- main kernel: R7 body, RPW=16, fully-resident grid ----------------
__device__ __forceinline__ float dot4(float4 a, float4 b, float acc) {
    acc = fmaf(a.x, b.x, acc);
    acc = fmaf(a.y, b.y, acc);
    acc = fmaf(a.z, b.z, acc);
    acc = fmaf(a.w, b.w, acc);
    return acc;
}

__global__ __launch_bounds__(256, 4) void sim_kernel(
    const float* __restrict__ query, const float* __restrict__ emb,
    const float* __restrict__ lut, float* __restrict__ out, int N)
{
    __shared__ float sLut[TABN];        // 2 KB: lut gathers become LDS reads (lgkmcnt),
    const int t = threadIdx.x;          // so prefetched global loads stay in flight
    for (int i = t; i < TABN; i += 256) sLut[i] = lut[i];
    __syncthreads();

    const int lane = t & 63;
    const int wave = blockIdx.x * 4 + (t >> 6);
    const size_t base0 = (size_t)wave * RPW;
    if (base0 >= (size_t)N) return;

    const float4 zero4 = make_float4(0.f, 0.f, 0.f, 0.f);
    const float4* q4 = (const float4*)query;
    float4 q0 = q4[lane];
    float4 q1 = q4[lane + 64];
    float4 q2 = q4[lane + 128];
    float4 q3 = (lane < DV4 - 192) ? q4[lane + 192] : zero4;

    float nq = 0.f;
    nq = dot4(q0, q0, nq); nq = dot4(q1, q1, nq);
    nq = dot4(q2, q2, nq); nq = dot4(q3, q3, nq);
#pragma unroll
    for (int off = 32; off >= 1; off >>= 1) nq += __shfl_xor(nq, off, 64);
    const float qn = sqrtf(nq);

    // named buffers (never arrays -> never scratch)
    float4 A0, A1, A2, A3, B0, B1, B2, B3;

#define LOADROW(P0, P1, P2, P3, ROW)                                    \
    {                                                                   \
        const float4* e4 = (const float4*)(emb + (size_t)(ROW) * D);    \
        P0 = e4[lane];                                                  \
        P1 = e4[lane + 64];                                             \
        P2 = e4[lane + 128];                                            \
        P3 = (lane < DV4 - 192) ? e4[lane + 192] : zero4;               \
    }

#define PROCROW(P0, P1, P2, P3, ROW)                                    \
    {                                                                   \
        float dt = 0.f, nn = 0.f;                                       \
        dt = dot4(P0, q0, dt); nn = dot4(P0, P0, nn);                   \
        dt = dot4(P1, q1, dt); nn = dot4(P1, P1, nn);                   \
        dt = dot4(P2, q2, dt); nn = dot4(P2, P2, nn);                   \
        dt = dot4(P3, q3, dt); nn = dot4(P3, P3, nn);                   \
        _Pragma("unroll")                                               \
        for (int off = 32; off >= 1; off >>= 1) {                       \
            dt += __shfl_xor(dt, off, 64);                              \
            nn += __shfl_xor(nn, off, 64);                              \
        }                                                               \
        /* butterfly broadcasts: all lanes compute (uniform) */         \
        float sim = dt / fmaxf(sqrtf(nn) * qn, 1e-8f);                  \
        float tt = (sim + 1.0f) * (0.5f * (float)(TABN - 1));           \
        tt = fminf(fmaxf(tt, 0.0f), (float)(TABN - 1));                 \
        int i0 = (int)tt;                                               \
        if (i0 > TABN - 2) i0 = TABN - 2;                               \
        float fr = tt - (float)i0;                                      \
        float v0 = sLut[i0], v1 = sLut[i0 + 1];                         \
        if (lane == 0) out[ROW] = fmaf(v1 - v0, fr, v0);                \
    }

    LOADROW(A0, A1, A2, A3, base0);
#pragma unroll 1
    for (int r = 0; r < RPW; r += 2) {
        LOADROW(B0, B1, B2, B3, base0 + r + 1);   // in flight during A's reduce
        PROCROW(A0, A1, A2, A3, base0 + r);
        if (r + 2 < RPW) LOADROW(A0, A1, A2, A3, base0 + r + 2);
        PROCROW(B0, B1, B2, B3, base0 + r + 1);
    }
#undef LOADROW
#undef PROCROW
}

extern "C" void kernel_launch(void* const* d_in, const int* in_sizes, int n_in,
                              void* d_out, int out_size, void* d_ws, size_t ws_size,
                              hipStream_t stream) {
    const float* query = (const float*)d_in[0];
    const float* emb   = (const float*)d_in[1];
    const float* w1    = (const float*)d_in[2];
    const float* b1    = (const float*)d_in[3];
    const float* w2    = (const float*)d_in[4];
    const float* b2    = (const float*)d_in[5];
    const float* w3    = (const float*)d_in[6];
    const float* b3    = (const float*)d_in[7];
    const float* w4    = (const float*)d_in[8];
    const float* b4    = (const float*)d_in[9];
    float* lut = (float*)d_ws;
    float* out = (float*)d_out;
    const int N = in_sizes[1] / D;   // 65536

    lut_kernel<<<TABN / LE, 256, 0, stream>>>(w1, b1, w2, b2, w3, b3, w4, b4, lut);

    const int waves  = (N + RPW - 1) / RPW;      // 4096
    const int blocks = (waves + 3) / 4;          // 1024 = 4 blocks/CU exactly
    sim_kernel<<<blocks, 256, 0, stream>>>(query, emb, lut, out, N);
}